// Round 9
// baseline (53.007 us; speedup 1.0000x reference)
//
#include <hip/hip_runtime.h>

// VQ lookup via bf16-split MFMA + top-2 + exact fp32 refine.
// N = 32768 queries, D = 128, K = 1024 codes, fp32 in/out.
// dot(z,c) ~= zh*ch + zh*cl + zl*ch  (3 accumulating bf16 MFMAs, fp32 acc)
// score = csq[k] - 2*dot ; per-lane top-2 (lex) ; exact fp32 refine of the 2.
//
// Round-9: BARRIER-FREE main loop. Codebook hi/lo fragments precomputed in
// fragment-stream layout: for (kt,kg,ks) a contiguous 2 KB block
// [H: 64 lanes x 16B][L: 64 lanes x 16B], so a wave's a-frag load is one
// coalesced 1 KB burst from L2. No LDS staging, no __syncthreads, no bank
// conflicts in the loop; 4 waves/SIMD TLP hides L2 latency independently.
// z-frags pinned in 64 VGPRs. LDS only for CSQ/RED/KWIN (~8.5 KB).
// Block: 512 thr = 8 waves (kg = w&3 over 16k, qgrp = w>>2 over 32q). QTI=64.

typedef __bf16 bf16x8_t __attribute__((ext_vector_type(8)));
typedef float f32x4_t __attribute__((ext_vector_type(4)));
typedef unsigned short us8_t __attribute__((ext_vector_type(8)));

#define NQ 32768
#define DIM 128
#define KCB 1024
#define QTI 64
#define KTI 64
#define NKT (KCB / KTI)

#define MFMA(a, b, c) __builtin_amdgcn_mfma_f32_16x16x32_bf16(a, b, c, 0, 0, 0)

__device__ __forceinline__ unsigned short bf16_rne(float f) {
    unsigned u = __float_as_uint(f);
    u = (u + 0x7FFFu + ((u >> 16) & 1u)) >> 16;
    return (unsigned short)u;
}

__device__ __forceinline__ bf16x8_t as_bf(f32x4_t v) {
    union { f32x4_t f; bf16x8_t b; } u; u.f = v; return u.b;
}

// 8 fp32 -> hi/lo bf16 packs via native casts (v_cvt_pk_bf16_f32)
__device__ __forceinline__ void cvt8(const float4 a, const float4 b,
                                     f32x4_t* hi, f32x4_t* lo) {
    float fv[8] = {a.x, a.y, a.z, a.w, b.x, b.y, b.z, b.w};
    bf16x8_t hb, lb;
    #pragma unroll
    for (int j = 0; j < 8; ++j) {
        __bf16 h = (__bf16)fv[j];
        hb[j] = h;
        lb[j] = (__bf16)(fv[j] - (float)h);
    }
    union { bf16x8_t b; f32x4_t f; } uh, ul;
    uh.b = hb; ul.b = lb;
    *hi = uh.f; *lo = ul.f;
}

// ---- prep: csq + codebook hi/lo split in fragment-stream global layout.
// For code k, chunk c (8 dims): kt=k>>6, kg=(k>>4)&3, ks=c>>2,
// lane=(c&3)*16+(k&15); block base = ((kt*4+kg)*4+ks)*2048;
// H at base+lane*16, L at base+1024+lane*16.
__global__ __launch_bounds__(256) void vq_prep_kernel(const float* __restrict__ cb,
                                                      float* __restrict__ csq,
                                                      unsigned short* __restrict__ cws) {
    const int t = threadIdx.x;
    const int k = blockIdx.x * 16 + (t >> 4);   // code row 0..1023
    const int chunk = t & 15;
    const float4* src = (const float4*)(cb + (size_t)k * DIM);
    float4 v0 = src[chunk * 2], v1 = src[chunk * 2 + 1];
    float fv[8] = {v0.x, v0.y, v0.z, v0.w, v1.x, v1.y, v1.z, v1.w};
    us8_t hv, lv;
    float ss = 0.f;
    #pragma unroll
    for (int j = 0; j < 8; ++j) {
        ss = fmaf(fv[j], fv[j], ss);
        unsigned short h = bf16_rne(fv[j]);
        hv[j] = h;
        lv[j] = bf16_rne(fv[j] - __uint_as_float((unsigned)h << 16));
    }
    #pragma unroll
    for (int off = 1; off < 16; off <<= 1) ss += __shfl_xor(ss, off);
    if (chunk == 0) csq[k] = ss;
    const int kt = k >> 6, kg = (k >> 4) & 3, ks = chunk >> 2;
    const int lane = (chunk & 3) * 16 + (k & 15);
    char* base = (char*)cws + (size_t)(((kt * 4 + kg) * 4 + ks)) * 2048 + lane * 16;
    *(us8_t*)base = hv;               // H
    *(us8_t*)(base + 1024) = lv;      // L
}

__global__ __launch_bounds__(512, 4) void vq_mfma_kernel(const float* __restrict__ z,
                                                         const float* __restrict__ cb,
                                                         const unsigned short* __restrict__ cws,
                                                         const float* __restrict__ csq,
                                                         float* __restrict__ out) {
    __shared__ float CSQ[KCB];       // 4 KB
    __shared__ float4 RED[4][QTI];   // 4 KB
    __shared__ int KWIN[QTI];        // 256 B

    const int t = threadIdx.x;
    const int l = t & 63;
    const int w = t >> 6;
    const int kg = w & 3;       // wave's k-group (16 k per tile)
    const int qgrp = w >> 2;    // wave's q-group (32 q each)
    const int qbase = blockIdx.x * QTI;

    if (t < KCB / 4) ((float4*)CSQ)[t] = ((const float4*)csq)[t];

    // ---- z fragments: direct global load in B-frag layout, hi/lo in-register
    f32x4_t zh[2][4], zl[2][4];
    #pragma unroll
    for (int qt = 0; qt < 2; ++qt)
        #pragma unroll
        for (int ks = 0; ks < 4; ++ks) {
            const int qrow = qgrp * 32 + qt * 16 + (l & 15);
            const int chunk = ks * 4 + (l >> 4);
            const float4* p = (const float4*)(z + (size_t)(qbase + qrow) * DIM + chunk * 8);
            cvt8(p[0], p[1], &zh[qt][ks], &zl[qt][ks]);
        }
    #pragma unroll
    for (int qt = 0; qt < 2; ++qt)
        #pragma unroll
        for (int ks = 0; ks < 4; ++ks)
            asm volatile("" : "+v"(zh[qt][ks]), "+v"(zl[qt][ks]));

    __syncthreads();   // CSQ visible; only barrier before the epilogue

    float s1[2], s2[2];
    int i1[2], i2[2];
    #pragma unroll
    for (int qt = 0; qt < 2; ++qt) { s1[qt] = 3.4e38f; s2[qt] = 3.4e38f; i1[qt] = 0; i2[qt] = 0; }

    const int grp4 = (l >> 4) * 4;
    // this wave's fragment stream: 4 ks-blocks of 2 KB per kt, tiles 8 KB apart
    const char* const wstream = (const char*)cws + (size_t)kg * 4 * 2048 + l * 16;

    #pragma unroll 1
    for (int kt = 0; kt < NKT; ++kt) {
        const char* p = wstream + (size_t)kt * 4 * 4 * 2048;

        // 8 coalesced 16B loads (1 KB/wave each), all issued before first use
        bf16x8_t ah[4], al[4];
        #pragma unroll
        for (int ks = 0; ks < 4; ++ks) {
            ah[ks] = *(const bf16x8_t*)(p + ks * 2048);
            al[ks] = *(const bf16x8_t*)(p + ks * 2048 + 1024);
        }

        const float4 cs0 = *(const float4*)&CSQ[kt * KTI + kg * 16 + grp4];

        f32x4_t acc[2];
        acc[0] = (f32x4_t){0.f, 0.f, 0.f, 0.f};
        acc[1] = (f32x4_t){0.f, 0.f, 0.f, 0.f};

        #pragma unroll
        for (int ks = 0; ks < 4; ++ks)
            #pragma unroll
            for (int qt = 0; qt < 2; ++qt) {
                acc[qt] = MFMA(ah[ks], as_bf(zh[qt][ks]), acc[qt]);
                acc[qt] = MFMA(ah[ks], as_bf(zl[qt][ks]), acc[qt]);
                acc[qt] = MFMA(al[ks], as_bf(zh[qt][ks]), acc[qt]);
            }

        // scores + per-lane top-2 (ascending k; strict < keeps earliest)
        #pragma unroll
        for (int qt = 0; qt < 2; ++qt)
            #pragma unroll
            for (int r = 0; r < 4; ++r) {
                int k = kt * KTI + kg * 16 + grp4 + r;
                float s = fmaf(-2.f, acc[qt][r], ((const float*)&cs0)[r]);
                if (s < s1[qt])      { s2[qt] = s1[qt]; i2[qt] = i1[qt]; s1[qt] = s; i1[qt] = k; }
                else if (s < s2[qt]) { s2[qt] = s; i2[qt] = k; }
            }
    }

    // intra-wave lex merge across the 4 lane-groups holding the same q
    #pragma unroll
    for (int qt = 0; qt < 2; ++qt) {
        float a1 = s1[qt], a2 = s2[qt];
        int j1 = i1[qt], j2 = i2[qt];
        #pragma unroll
        for (int off = 16; off < 64; off <<= 1) {
            float b1 = __shfl_xor(a1, off);
            float b2 = __shfl_xor(a2, off);
            int m1 = __shfl_xor(j1, off);
            int m2 = __shfl_xor(j2, off);
            bool bw = (b1 < a1) || (b1 == a1 && m1 < j1);
            float w1 = bw ? b1 : a1; int x1 = bw ? m1 : j1;
            float lb = bw ? a1 : b1; int ly = bw ? j1 : m1;   // loser's best
            float ws = bw ? b2 : a2; int wy = bw ? m2 : j2;   // winner's 2nd
            bool sw = (lb < ws) || (lb == ws && ly < wy);
            a1 = w1; j1 = x1;
            a2 = sw ? lb : ws; j2 = sw ? ly : wy;
        }
        if (l < 16)
            RED[kg][qgrp * 32 + qt * 16 + l] =
                make_float4(a1, __int_as_float(j1), a2, __int_as_float(j2));
    }
    __syncthreads();

    // final merge across 4 k-groups + exact fp32 refine (one thread per q)
    if (t < QTI) {
        float4 e = RED[0][t];
        float a1 = e.x, a2 = e.z;
        int j1 = __float_as_int(e.y), j2 = __float_as_int(e.w);
        #pragma unroll
        for (int g = 1; g < 4; ++g) {
            float4 f = RED[g][t];
            float b1 = f.x, b2 = f.z;
            int m1 = __float_as_int(f.y), m2 = __float_as_int(f.w);
            bool bw = (b1 < a1) || (b1 == a1 && m1 < j1);
            float w1 = bw ? b1 : a1; int x1 = bw ? m1 : j1;
            float lb = bw ? a1 : b1; int ly = bw ? j1 : m1;
            float ws = bw ? b2 : a2; int wy = bw ? m2 : j2;
            bool sw = (lb < ws) || (lb == ws && ly < wy);
            a1 = w1; j1 = x1;
            a2 = sw ? lb : ws; j2 = sw ? ly : wy;
        }
        const float* zr = z + (size_t)(qbase + t) * DIM;
        const float* c1 = cb + (size_t)j1 * DIM;
        const float* c2 = cb + (size_t)j2 * DIM;
        float p1 = 0.f, q1 = 0.f, p2 = 0.f, q2 = 0.f;
        #pragma unroll
        for (int d = 0; d < DIM; d += 4) {
            float4 zv = *(const float4*)(zr + d);
            float4 u = *(const float4*)(c1 + d);
            float4 v = *(const float4*)(c2 + d);
            p1 = fmaf(zv.x, u.x, p1); q1 = fmaf(zv.y, u.y, q1);
            p1 = fmaf(zv.z, u.z, p1); q1 = fmaf(zv.w, u.w, q1);
            p2 = fmaf(zv.x, v.x, p2); q2 = fmaf(zv.y, v.y, q2);
            p2 = fmaf(zv.z, v.z, p2); q2 = fmaf(zv.w, v.w, q2);
        }
        float e1 = fmaf(-2.f, p1 + q1, CSQ[j1]);
        float e2 = fmaf(-2.f, p2 + q2, CSQ[j2]);
        KWIN[t] = (e1 < e2 || (e1 == e2 && j1 < j2)) ? j1 : j2;
    }
    __syncthreads();

    {   // gather winning codebook rows (8 threads per row)
        const int srow = t >> 3;
        const int scol = t & 7;
        const float4* src = (const float4*)(cb + (size_t)KWIN[srow] * DIM);
        float4* dst = (float4*)(out + (size_t)(qbase + srow) * DIM);
        #pragma unroll
        for (int i = 0; i < 4; ++i) dst[scol + 8 * i] = src[scol + 8 * i];
    }
}

extern "C" void kernel_launch(void* const* d_in, const int* in_sizes, int n_in,
                              void* d_out, int out_size, void* d_ws, size_t ws_size,
                              hipStream_t stream) {
    const float* z  = (const float*)d_in[0];   // inputs [32,32,32,128]
    const float* cb = (const float*)d_in[1];   // codebook [1024,128]
    float* csq = (float*)d_ws;                             // 4 KB
    unsigned short* cws = (unsigned short*)((char*)d_ws + 4096);  // 512 KB frag stream
    float* out = (float*)d_out;

    vq_prep_kernel<<<KCB / 16, 256, 0, stream>>>(cb, csq, cws);
    vq_mfma_kernel<<<NQ / QTI, 512, 0, stream>>>(z, cb, cws, csq, out);
}